// Round 10
// baseline (317.981 us; speedup 1.0000x reference)
//
#include <hip/hip_runtime.h>
#include <hip/hip_bf16.h>

#define D 256
typedef unsigned short u16;
typedef __attribute__((ext_vector_type(8))) short bf16x8;
typedef __attribute__((ext_vector_type(4))) float f32x4;

__device__ inline u16 f2bf(float f) {
    unsigned u = __builtin_bit_cast(unsigned, f);
    unsigned r = (u + 0x7fff + ((u >> 16) & 1)) >> 16;   // RNE
    return (u16)r;
}
__device__ inline float bf2f(u16 u) {
    return __builtin_bit_cast(float, (unsigned)u << 16);
}

// ------------------------------ per-relation CSR build ------------------------------
// key = rel*N + src for rel in [0,4); rel 4 edges dropped (never aggregated).

__global__ void hist_kernel(const int* __restrict__ src, const int* __restrict__ et,
                            int* __restrict__ cnt, int E, int N) {
    int e = blockIdx.x * blockDim.x + threadIdx.x;
    if (e < E) {
        int r = et[e];
        if (r < 4) atomicAdd(&cnt[r * N + src[e]], 1);
    }
}

#define SCAN_BLK 4096

__global__ __launch_bounds__(256) void scan_reduce_kernel(const int* __restrict__ cnt,
        int* __restrict__ bsum, int n) {
    __shared__ int s[256];
    int base = blockIdx.x * SCAN_BLK;
    int t = threadIdx.x;
    int sum = 0;
    for (int i = t; i < SCAN_BLK; i += 256) {
        int idx = base + i;
        if (idx < n) sum += cnt[idx];
    }
    s[t] = sum;
    __syncthreads();
    for (int off = 128; off > 0; off >>= 1) {
        if (t < off) s[t] += s[t + off];
        __syncthreads();
    }
    if (t == 0) bsum[blockIdx.x] = s[0];
}

__global__ __launch_bounds__(256) void scan_sums_kernel(const int* __restrict__ bsum,
        int* __restrict__ boff, int nb, int* __restrict__ row_ptr, int n) {
    __shared__ int s[256];
    int t = threadIdx.x;
    s[t] = (t < nb) ? bsum[t] : 0;
    __syncthreads();
    for (int off = 1; off < 256; off <<= 1) {
        int v = (t >= off) ? s[t - off] : 0;
        __syncthreads();
        s[t] += v;
        __syncthreads();
    }
    if (t < nb) boff[t] = (t == 0) ? 0 : s[t - 1];
    if (t == 255) row_ptr[n] = s[255];
}

__global__ __launch_bounds__(256) void scan_out_kernel(const int* __restrict__ cnt,
        const int* __restrict__ boff, int* __restrict__ row_ptr,
        int* __restrict__ row_cur, int n) {
    __shared__ int stage[SCAN_BLK];
    __shared__ int part[256];
    int base = blockIdx.x * SCAN_BLK;
    int t = threadIdx.x;
    for (int i = t; i < SCAN_BLK; i += 256) {
        int idx = base + i;
        stage[i] = (idx < n) ? cnt[idx] : 0;
    }
    __syncthreads();
    int loc = 0;
#pragma unroll
    for (int j = 0; j < 16; ++j) loc += stage[t * 16 + j];
    part[t] = loc;
    __syncthreads();
    for (int off = 1; off < 256; off <<= 1) {
        int v = (t >= off) ? part[t - off] : 0;
        __syncthreads();
        part[t] += v;
        __syncthreads();
    }
    int run = boff[blockIdx.x] + ((t == 0) ? 0 : part[t - 1]);
#pragma unroll
    for (int j = 0; j < 16; ++j) {
        int idx = base + t * 16 + j;
        if (idx < n) {
            row_ptr[idx] = run;
            row_cur[idx] = run;
        }
        run += stage[t * 16 + j];
    }
}

__global__ void scatter_kernel(const int* __restrict__ src, const int* __restrict__ dst,
        const int* __restrict__ et, int* __restrict__ row_cur, int* __restrict__ eperm,
        int E, int N) {
    int e = blockIdx.x * blockDim.x + threadIdx.x;
    if (e < E) {
        int r = et[e];
        if (r < 4) {
            int pos = atomicAdd(&row_cur[r * N + src[e]], 1);
            eperm[pos] = dst[e];
        }
    }
}

// ------------------------------ fused prep ------------------------------

__global__ __launch_bounds__(256) void prep_kernel(const float* __restrict__ x,
        const float* __restrict__ rel_W, const float* __restrict__ root_W,
        const float* __restrict__ fc1_w, const float* __restrict__ fc2_w,
        u16* __restrict__ xb, u16* __restrict__ Bcat, u16* __restrict__ fc2t, int N) {
    int i = blockIdx.x * 256 + threadIdx.x;
    int nx = N * 64;                       // float4 count
    if (i < nx) {
        float4 v = reinterpret_cast<const float4*>(x)[i];
        ushort4 o;
        o.x = f2bf(v.x); o.y = f2bf(v.y); o.z = f2bf(v.z); o.w = f2bf(v.w);
        reinterpret_cast<ushort4*>(xb)[i] = o;
        return;
    }
    int j = i - nx;
    if (j < 5 * 131072) {
        int mi = j >> 17;                  // matrix 0..4
        int t = j & 131071;
        int k = t & 511;
        int n = t >> 9;                    // 0..255
        float v;
        if (mi < 4) {
            v = (k < 256) ? rel_W[(((size_t)mi * 5 + mi) * 256 + k) * 256 + n]
                          : root_W[((size_t)mi * 256 + (k - 256)) * 256 + n];
        } else {
            v = fc1_w[(size_t)k * 256 + n];
        }
        Bcat[(size_t)mi * 131072 + (size_t)n * 512 + k] = f2bf(v);
        return;
    }
    int h = j - 5 * 131072;
    if (h < 4096) {
        int k = h & 255;
        int col = h >> 8;
        fc2t[(size_t)col * 256 + k] = f2bf(fc2_w[(size_t)k * 16 + col]);
    }
}

// ------------------------------ mean aggregation (pure gather) ------------------------------

__global__ __launch_bounds__(256) void agg_kernel(const u16* __restrict__ h,
        const int* __restrict__ rpA, const int* __restrict__ rpB,
        const int* __restrict__ eperm,
        u16* __restrict__ outA, u16* __restrict__ outB, int N) {
    int node = blockIdx.x * 4 + (threadIdx.x >> 6);
    int lane = threadIdx.x & 63;
    if (node >= N) return;
    const int* rp = (blockIdx.y == 0) ? rpA : rpB;
    u16* outp     = (blockIdx.y == 0) ? outA : outB;

    int beg = rp[node];
    int end = rp[node + 1];
    float a0 = 0.f, a1 = 0.f, a2 = 0.f, a3 = 0.f;
    for (int e = beg; e < end; ++e) {
        int d = eperm[e];
        ushort4 v = *reinterpret_cast<const ushort4*>(h + (size_t)d * 256 + lane * 4);
        a0 += bf2f(v.x); a1 += bf2f(v.y); a2 += bf2f(v.z); a3 += bf2f(v.w);
    }
    float inv = 1.0f / fmaxf((float)(end - beg), 1.0f);
    ushort4 o;
    o.x = f2bf(a0 * inv);
    o.y = f2bf(a1 * inv);
    o.z = f2bf(a2 * inv);
    o.w = f2bf(a3 * inv);
    *reinterpret_cast<ushort4*>(outp + (size_t)node * 256 + lane * 4) = o;
}

// ------------------------------ bf16 MFMA GEMM (K=512, NN=256) ------------------------------
// out[m, coff+n] = relu( sum_k A[m,k]*Bt[n,k] + bias[n] ), A = [Alo | Ahi] split at k=256.
// Tile: BM=128 (4 waves x 32 rows: two 16-row subtiles/wave), BN=128, BK=64.
// One B-stage (16 KB, XOR-swizzled) feeds 32 MFMAs/wave/K-step; each ds_read bfr
// is shared by both row-subtiles (acc[rt][j]).

__global__ __launch_bounds__(256) void gemm512(
        const u16* __restrict__ Alo, int ldlo, const u16* __restrict__ Ahi, int ldhi,
        const u16* __restrict__ Bt, int M,
        u16* __restrict__ outp, int ldo, int coff, const float* __restrict__ bias) {
    __shared__ u16 Bs[128 * 64];   // 16 KB, physically swizzled

    const int tid  = threadIdx.x;
    const int wave = tid >> 6, lane = tid & 63;
    const int l15 = lane & 15, lg = lane >> 4;
    const int m0 = blockIdx.x * 128 + wave * 32;
    const int n0 = blockIdx.y * 128;

    f32x4 acc[2][8];
#pragma unroll
    for (int rt = 0; rt < 2; ++rt)
#pragma unroll
        for (int j = 0; j < 8; ++j) acc[rt][j] = (f32x4){0.f, 0.f, 0.f, 0.f};

    const int arow0 = m0 + l15;
    const int arow1 = arow0 + 16;
    const bool av0 = arow0 < M;
    const bool av1 = arow1 < M;

#pragma unroll
    for (int k0 = 0; k0 < 512; k0 += 64) {
        __syncthreads();
#pragma unroll
        for (int i = 0; i < 4; ++i) {
            int phys = i * 4096 + tid * 16;
            int n    = phys >> 7;                       // B-row within tile (128 B rows)
            int cl   = (phys & 127) ^ ((n & 7) << 4);   // logical byte within row
            const u16* srcp = Bt + (size_t)(n0 + n) * 512 + k0 + (cl >> 1);
            __builtin_amdgcn_global_load_lds(
                (const __attribute__((address_space(1))) void*)srcp,
                (__attribute__((address_space(3))) void*)((char*)Bs + phys), 16, 0, 0);
        }
        const u16* Ab0 = (k0 < 256) ? (Alo + (size_t)arow0 * ldlo + k0)
                                    : (Ahi + (size_t)arow0 * ldhi + (k0 - 256));
        const u16* Ab1 = (k0 < 256) ? (Alo + (size_t)arow1 * ldlo + k0)
                                    : (Ahi + (size_t)arow1 * ldhi + (k0 - 256));
        bf16x8 afr[2][2];
        const bf16x8 z = (bf16x8){0, 0, 0, 0, 0, 0, 0, 0};
        afr[0][0] = av0 ? *reinterpret_cast<const bf16x8*>(Ab0 + lg * 8)      : z;
        afr[0][1] = av0 ? *reinterpret_cast<const bf16x8*>(Ab0 + 32 + lg * 8) : z;
        afr[1][0] = av1 ? *reinterpret_cast<const bf16x8*>(Ab1 + lg * 8)      : z;
        afr[1][1] = av1 ? *reinterpret_cast<const bf16x8*>(Ab1 + 32 + lg * 8) : z;
        __syncthreads();   // drains vmcnt(0) -> staged tile ready
#pragma unroll
        for (int kk = 0; kk < 2; ++kk) {
#pragma unroll
            for (int j = 0; j < 8; ++j) {
                int n    = j * 16 + l15;
                int cl   = kk * 64 + lg * 16;
                int phys = n * 128 + (cl ^ ((n & 7) << 4));
                bf16x8 bfr = *reinterpret_cast<const bf16x8*>((const char*)Bs + phys);
                acc[0][j] = __builtin_amdgcn_mfma_f32_16x16x32_bf16(afr[0][kk], bfr, acc[0][j], 0, 0, 0);
                acc[1][j] = __builtin_amdgcn_mfma_f32_16x16x32_bf16(afr[1][kk], bfr, acc[1][j], 0, 0, 0);
            }
        }
    }

    // epilogue: D col = lane&15, row = (lane>>4)*4 + reg  [m89/m91 verified]
#pragma unroll
    for (int rt = 0; rt < 2; ++rt) {
        const int orow = m0 + rt * 16 + lg * 4;
#pragma unroll
        for (int j = 0; j < 8; ++j) {
            int gn = n0 + j * 16 + l15;
            float b = bias[gn];
#pragma unroll
            for (int r = 0; r < 4; ++r) {
                int m = orow + r;
                if (m >= M) continue;
                float v = fmaxf(acc[rt][j][r] + b, 0.0f);
                outp[(size_t)m * ldo + coff + gn] = f2bf(v);
            }
        }
    }
}

// ------------------------------ fc2 + log_softmax head (MFMA) ------------------------------

__global__ __launch_bounds__(256) void head_mfma_kernel(const u16* __restrict__ hid,
        const u16* __restrict__ w2t, const float* __restrict__ b2,
        float* __restrict__ out, int N) {
    int tile = blockIdx.x * 4 + (threadIdx.x >> 6);   // 16 nodes per tile
    int lane = threadIdx.x & 63;
    int l15 = lane & 15, lg = lane >> 4;
    int ntiles = (N + 15) / 16;
    if (tile >= ntiles) return;

    int anode = tile * 16 + l15;
    if (anode >= N) anode = N - 1;                    // clamp (dup compute, guarded store)
    const u16* Arow = hid + (size_t)anode * 256;
    const u16* Brow = w2t + (size_t)l15 * 256;        // col = l15

    f32x4 acc = (f32x4){0.f, 0.f, 0.f, 0.f};
#pragma unroll
    for (int k0 = 0; k0 < 256; k0 += 32) {
        bf16x8 a = *reinterpret_cast<const bf16x8*>(Arow + k0 + lg * 8);
        bf16x8 b = *reinterpret_cast<const bf16x8*>(Brow + k0 + lg * 8);
        acc = __builtin_amdgcn_mfma_f32_16x16x32_bf16(a, b, acc, 0, 0, 0);
    }
    float bcol = b2[l15];
#pragma unroll
    for (int r = 0; r < 4; ++r) {
        float v = acc[r] + bcol;
        float mx = v;
        mx = fmaxf(mx, __shfl_xor(mx, 1));
        mx = fmaxf(mx, __shfl_xor(mx, 2));
        mx = fmaxf(mx, __shfl_xor(mx, 4));
        mx = fmaxf(mx, __shfl_xor(mx, 8));
        float e = expf(v - mx);
        float s = e;
        s += __shfl_xor(s, 1);
        s += __shfl_xor(s, 2);
        s += __shfl_xor(s, 4);
        s += __shfl_xor(s, 8);
        float lse = mx + logf(s);
        int row = tile * 16 + lg * 4 + r;
        if (row < N) out[(size_t)row * 16 + l15] = v - lse;
    }
}

// ------------------------------ launch ------------------------------

extern "C" void kernel_launch(void* const* d_in, const int* in_sizes, int n_in,
                              void* d_out, int out_size, void* d_ws, size_t ws_size,
                              hipStream_t stream) {
    const float* x      = (const float*)d_in[0];
    const int*   ei     = (const int*)d_in[1];
    const int*   et     = (const int*)d_in[2];
    const float* rel_W  = (const float*)d_in[3];
    const float* root_W = (const float*)d_in[4];
    const float* bias   = (const float*)d_in[5];
    const float* fc1_w  = (const float*)d_in[6];
    const float* fc1_b  = (const float*)d_in[7];
    const float* fc2_w  = (const float*)d_in[8];
    const float* fc2_b  = (const float*)d_in[9];
    float* out = (float*)d_out;

    const int N = in_sizes[0] / D;   // 20000
    const int E = in_sizes[2];       // 500000
    const int* src = ei;
    const int* dst = ei + E;

    char* w = (char*)d_ws;
    u16* xb    = (u16*)w;  w += (size_t)N * 256 * 2;
    u16* h1b   = (u16*)w;  w += (size_t)N * 256 * 2;
    u16* hcatb = (u16*)w;  w += (size_t)N * 512 * 2;
    u16* aggA  = (u16*)w;  w += (size_t)N * 256 * 2;
    u16* aggB  = (u16*)w;  w += (size_t)N * 256 * 2;
    u16* Bcat  = (u16*)w;  w += (size_t)5 * 256 * 512 * 2;
    u16* fc2t  = (u16*)w;  w += (size_t)16 * 256 * 2;
    int* cnt     = (int*)w;  w += (size_t)4 * N * 4;
    int* row_ptr = (int*)w;  w += ((size_t)4 * N + 1) * 4;
    int* row_cur = (int*)w;  w += (size_t)4 * N * 4;
    int* eperm   = (int*)w;  w += (size_t)E * 4;
    int* bsum    = (int*)w;  w += 256 * 4;
    int* boff    = (int*)w;  w += 256 * 4;
    u16* hid = h1b;   // reuse after convs

    const int n_keys = 4 * N;
    const int nb = (n_keys + SCAN_BLK - 1) / SCAN_BLK;   // 20 for N=20000

    // per-relation CSR
    hipMemsetAsync(cnt, 0, (size_t)n_keys * 4, stream);
    hist_kernel<<<dim3((E + 255) / 256), dim3(256), 0, stream>>>(src, et, cnt, E, N);
    scan_reduce_kernel<<<dim3(nb), dim3(256), 0, stream>>>(cnt, bsum, n_keys);
    scan_sums_kernel<<<dim3(1), dim3(256), 0, stream>>>(bsum, boff, nb, row_ptr, n_keys);
    scan_out_kernel<<<dim3(nb), dim3(256), 0, stream>>>(cnt, boff, row_ptr, row_cur, n_keys);
    scatter_kernel<<<dim3((E + 255) / 256), dim3(256), 0, stream>>>(src, dst, et, row_cur, eperm, E, N);

    // fused prep
    {
        int total = N * 64 + 5 * 131072 + 4096;
        prep_kernel<<<dim3((total + 255) / 256), dim3(256), 0, stream>>>(
                x, rel_W, root_W, fc1_w, fc2_w, xb, Bcat, fc2t, N);
    }

    dim3 gblock(256);
    dim3 ngrid1((N + 3) / 4, 1);
    dim3 ngrid2((N + 3) / 4, 2);
    dim3 ggrid((N + 127) / 128, 2);    // BM=128, BN=128, NN=256

    // hop-0 aggregations for both metapaths read only x -> fused dual launch
    agg_kernel<<<ngrid2, gblock, 0, stream>>>(xb, row_ptr, row_ptr + 2 * N, eperm, aggA, aggB, N);

    // mp0 hop0: h1 = relu([aggA|x] @ [W0;R0] + b0)
    gemm512<<<ggrid, gblock, 0, stream>>>(aggA, 256, xb, 256, Bcat + 0 * 131072, N,
                                          h1b, 256, 0, bias + 0 * 256);
    // mp0 hop1
    agg_kernel<<<ngrid1, gblock, 0, stream>>>(h1b, row_ptr + 1 * N, row_ptr + 1 * N, eperm, aggA, aggA, N);
    gemm512<<<ggrid, gblock, 0, stream>>>(aggA, 256, h1b, 256, Bcat + 1 * 131072, N,
                                          hcatb, 512, 0, bias + 1 * 256);
    // mp1 hop0: h1' = relu([aggB|x] @ [W2;R2] + b2)
    gemm512<<<ggrid, gblock, 0, stream>>>(aggB, 256, xb, 256, Bcat + 2 * 131072, N,
                                          h1b, 256, 0, bias + 2 * 256);
    // mp1 hop1
    agg_kernel<<<ngrid1, gblock, 0, stream>>>(h1b, row_ptr + 3 * N, row_ptr + 3 * N, eperm, aggA, aggA, N);
    gemm512<<<ggrid, gblock, 0, stream>>>(aggA, 256, h1b, 256, Bcat + 3 * 131072, N,
                                          hcatb, 512, 256, bias + 3 * 256);
    // fc1: hid = relu(hcat @ fc1 + b), A = hcat split halves
    gemm512<<<ggrid, gblock, 0, stream>>>(hcatb, 512, hcatb + 256, 512, Bcat + 4 * 131072, N,
                                          hid, 256, 0, fc1_b);
    // head
    int ntiles = (N + 15) / 16;
    head_mfma_kernel<<<dim3((ntiles + 3) / 4), gblock, 0, stream>>>(hid, fc2t, fc2_b, out, N);
}

// Round 11
// 288.596 us; speedup vs baseline: 1.1018x; 1.1018x over previous
//
#include <hip/hip_runtime.h>
#include <hip/hip_bf16.h>

#define D 256
typedef unsigned short u16;
typedef __attribute__((ext_vector_type(8))) short bf16x8;
typedef __attribute__((ext_vector_type(4))) float f32x4;

__device__ inline u16 f2bf(float f) {
    unsigned u = __builtin_bit_cast(unsigned, f);
    unsigned r = (u + 0x7fff + ((u >> 16) & 1)) >> 16;   // RNE
    return (u16)r;
}
__device__ inline float bf2f(u16 u) {
    return __builtin_bit_cast(float, (unsigned)u << 16);
}

// ------------------------------ per-relation CSR build ------------------------------

__global__ void hist_kernel(const int* __restrict__ src, const int* __restrict__ et,
                            int* __restrict__ cnt, int E, int N) {
    int e = blockIdx.x * blockDim.x + threadIdx.x;
    if (e < E) {
        int r = et[e];
        if (r < 4) atomicAdd(&cnt[r * N + src[e]], 1);
    }
}

#define SCAN_BLK 4096

__global__ __launch_bounds__(256) void scan_reduce_kernel(const int* __restrict__ cnt,
        int* __restrict__ bsum, int n) {
    __shared__ int s[256];
    int base = blockIdx.x * SCAN_BLK;
    int t = threadIdx.x;
    int sum = 0;
    for (int i = t; i < SCAN_BLK; i += 256) {
        int idx = base + i;
        if (idx < n) sum += cnt[idx];
    }
    s[t] = sum;
    __syncthreads();
    for (int off = 128; off > 0; off >>= 1) {
        if (t < off) s[t] += s[t + off];
        __syncthreads();
    }
    if (t == 0) bsum[blockIdx.x] = s[0];
}

__global__ __launch_bounds__(256) void scan_sums_kernel(const int* __restrict__ bsum,
        int* __restrict__ boff, int nb, int* __restrict__ row_ptr, int n) {
    __shared__ int s[256];
    int t = threadIdx.x;
    s[t] = (t < nb) ? bsum[t] : 0;
    __syncthreads();
    for (int off = 1; off < 256; off <<= 1) {
        int v = (t >= off) ? s[t - off] : 0;
        __syncthreads();
        s[t] += v;
        __syncthreads();
    }
    if (t < nb) boff[t] = (t == 0) ? 0 : s[t - 1];
    if (t == 255) row_ptr[n] = s[255];
}

__global__ __launch_bounds__(256) void scan_out_kernel(const int* __restrict__ cnt,
        const int* __restrict__ boff, int* __restrict__ row_ptr,
        int* __restrict__ row_cur, int n) {
    __shared__ int stage[SCAN_BLK];
    __shared__ int part[256];
    int base = blockIdx.x * SCAN_BLK;
    int t = threadIdx.x;
    for (int i = t; i < SCAN_BLK; i += 256) {
        int idx = base + i;
        stage[i] = (idx < n) ? cnt[idx] : 0;
    }
    __syncthreads();
    int loc = 0;
#pragma unroll
    for (int j = 0; j < 16; ++j) loc += stage[t * 16 + j];
    part[t] = loc;
    __syncthreads();
    for (int off = 1; off < 256; off <<= 1) {
        int v = (t >= off) ? part[t - off] : 0;
        __syncthreads();
        part[t] += v;
        __syncthreads();
    }
    int run = boff[blockIdx.x] + ((t == 0) ? 0 : part[t - 1]);
#pragma unroll
    for (int j = 0; j < 16; ++j) {
        int idx = base + t * 16 + j;
        if (idx < n) {
            row_ptr[idx] = run;
            row_cur[idx] = run;
        }
        run += stage[t * 16 + j];
    }
}

__global__ void scatter_kernel(const int* __restrict__ src, const int* __restrict__ dst,
        const int* __restrict__ et, int* __restrict__ row_cur, int* __restrict__ eperm,
        int E, int N) {
    int e = blockIdx.x * blockDim.x + threadIdx.x;
    if (e < E) {
        int r = et[e];
        if (r < 4) {
            int pos = atomicAdd(&row_cur[r * N + src[e]], 1);
            eperm[pos] = dst[e];
        }
    }
}

// ------------------------------ fused prep ------------------------------

__global__ __launch_bounds__(256) void prep_kernel(const float* __restrict__ x,
        const float* __restrict__ rel_W, const float* __restrict__ root_W,
        const float* __restrict__ fc1_w, const float* __restrict__ fc2_w,
        u16* __restrict__ xb, u16* __restrict__ Bcat, u16* __restrict__ fc2t, int N) {
    int i = blockIdx.x * 256 + threadIdx.x;
    int nx = N * 64;                       // float4 count
    if (i < nx) {
        float4 v = reinterpret_cast<const float4*>(x)[i];
        ushort4 o;
        o.x = f2bf(v.x); o.y = f2bf(v.y); o.z = f2bf(v.z); o.w = f2bf(v.w);
        reinterpret_cast<ushort4*>(xb)[i] = o;
        return;
    }
    int j = i - nx;
    if (j < 5 * 131072) {
        int mi = j >> 17;                  // matrix 0..4
        int t = j & 131071;
        int k = t & 511;
        int n = t >> 9;                    // 0..255
        float v;
        if (mi < 4) {
            v = (k < 256) ? rel_W[(((size_t)mi * 5 + mi) * 256 + k) * 256 + n]
                          : root_W[((size_t)mi * 256 + (k - 256)) * 256 + n];
        } else {
            v = fc1_w[(size_t)k * 256 + n];
        }
        Bcat[(size_t)mi * 131072 + (size_t)n * 512 + k] = f2bf(v);
        return;
    }
    int h = j - 5 * 131072;
    if (h < 4096) {
        int k = h & 255;
        int col = h >> 8;
        fc2t[(size_t)col * 256 + k] = f2bf(fc2_w[(size_t)k * 16 + col]);
    }
}

// ------------------------------ mean aggregation (dual, pure gather) ------------------------------
// blockIdx.y selects (hA,rpA,outA) vs (hB,rpB,outB); fp32 accum, bf16 in/out.

__global__ __launch_bounds__(256) void agg_kernel(
        const u16* __restrict__ hA, const u16* __restrict__ hB,
        const int* __restrict__ rpA, const int* __restrict__ rpB,
        const int* __restrict__ eperm,
        u16* __restrict__ outA, u16* __restrict__ outB, int N) {
    int node = blockIdx.x * 4 + (threadIdx.x >> 6);
    int lane = threadIdx.x & 63;
    if (node >= N) return;
    const u16* h  = (blockIdx.y == 0) ? hA : hB;
    const int* rp = (blockIdx.y == 0) ? rpA : rpB;
    u16* outp     = (blockIdx.y == 0) ? outA : outB;

    int beg = rp[node];
    int end = rp[node + 1];
    float a0 = 0.f, a1 = 0.f, a2 = 0.f, a3 = 0.f;
    for (int e = beg; e < end; ++e) {
        int d = eperm[e];
        ushort4 v = *reinterpret_cast<const ushort4*>(h + (size_t)d * 256 + lane * 4);
        a0 += bf2f(v.x); a1 += bf2f(v.y); a2 += bf2f(v.z); a3 += bf2f(v.w);
    }
    float inv = 1.0f / fmaxf((float)(end - beg), 1.0f);
    ushort4 o;
    o.x = f2bf(a0 * inv);
    o.y = f2bf(a1 * inv);
    o.z = f2bf(a2 * inv);
    o.w = f2bf(a3 * inv);
    *reinterpret_cast<ushort4*>(outp + (size_t)node * 256 + lane * 4) = o;
}

// ------------------------------ bf16 MFMA GEMM (K=512, NN=256, z-batched) ------------------------------
// out[m, coff+n] = relu( sum_k A[m,k]*Bt[n,k] + bias[n] ), A = [Alo | Ahi] split at k=256.
// BM=64 (4 waves x 16 rows), BN=128, BK=64 — proven 301us config. blockIdx.z
// selects one of two independent GEMMs (wave-uniform SGPR selects); gridDim.z=1
// for a single GEMM.

__global__ __launch_bounds__(256) void gemm512b(
        const u16* __restrict__ Alo0, const u16* __restrict__ Alo1, int ldlo,
        const u16* __restrict__ Ahi0, const u16* __restrict__ Ahi1, int ldhi,
        const u16* __restrict__ Bt0, const u16* __restrict__ Bt1, int M,
        u16* __restrict__ out0, u16* __restrict__ out1, int ldo, int coff1,
        const float* __restrict__ bias0, const float* __restrict__ bias1) {
    __shared__ u16 Bs[128 * 64];   // 16 KB, physically swizzled

    const int z = blockIdx.z;
    const u16* Alo = z ? Alo1 : Alo0;
    const u16* Ahi = z ? Ahi1 : Ahi0;
    const u16* Bt  = z ? Bt1  : Bt0;
    u16* outp      = z ? out1 : out0;
    const float* bias = z ? bias1 : bias0;
    const int coff = z ? coff1 : 0;

    const int tid  = threadIdx.x;
    const int wave = tid >> 6, lane = tid & 63;
    const int l15 = lane & 15, lg = lane >> 4;
    const int m0 = blockIdx.x * 64 + wave * 16;
    const int n0 = blockIdx.y * 128;

    f32x4 acc[8];
#pragma unroll
    for (int j = 0; j < 8; ++j) acc[j] = (f32x4){0.f, 0.f, 0.f, 0.f};

    const int  arow = m0 + l15;
    const bool aval = arow < M;

#pragma unroll
    for (int k0 = 0; k0 < 512; k0 += 64) {
        __syncthreads();
#pragma unroll
        for (int i = 0; i < 4; ++i) {
            int phys = i * 4096 + tid * 16;
            int n    = phys >> 7;                       // B-row within tile (128 B rows)
            int cl   = (phys & 127) ^ ((n & 7) << 4);   // logical byte within row
            const u16* srcp = Bt + (size_t)(n0 + n) * 512 + k0 + (cl >> 1);
            __builtin_amdgcn_global_load_lds(
                (const __attribute__((address_space(1))) void*)srcp,
                (__attribute__((address_space(3))) void*)((char*)Bs + phys), 16, 0, 0);
        }
        const u16* Ab = (k0 < 256) ? (Alo + (size_t)arow * ldlo + k0)
                                   : (Ahi + (size_t)arow * ldhi + (k0 - 256));
        bf16x8 afr0, afr1;
        if (aval) {
            afr0 = *reinterpret_cast<const bf16x8*>(Ab + lg * 8);
            afr1 = *reinterpret_cast<const bf16x8*>(Ab + 32 + lg * 8);
        } else {
            afr0 = afr1 = (bf16x8){0, 0, 0, 0, 0, 0, 0, 0};
        }
        __syncthreads();   // drains vmcnt(0) -> staged tile ready
#pragma unroll
        for (int kk = 0; kk < 2; ++kk) {
#pragma unroll
            for (int j = 0; j < 8; ++j) {
                int n    = j * 16 + l15;
                int cl   = kk * 64 + lg * 16;
                int phys = n * 128 + (cl ^ ((n & 7) << 4));
                bf16x8 bfr = *reinterpret_cast<const bf16x8*>((const char*)Bs + phys);
                acc[j] = __builtin_amdgcn_mfma_f32_16x16x32_bf16(kk ? afr1 : afr0, bfr, acc[j], 0, 0, 0);
            }
        }
    }

    // epilogue: D col = lane&15, row = (lane>>4)*4 + reg  [m89/m91 verified]
    const int orow = m0 + lg * 4;
#pragma unroll
    for (int j = 0; j < 8; ++j) {
        int gn = n0 + j * 16 + l15;
        float b = bias[gn];
#pragma unroll
        for (int r = 0; r < 4; ++r) {
            int m = orow + r;
            if (m >= M) continue;
            float v = fmaxf(acc[j][r] + b, 0.0f);
            outp[(size_t)m * ldo + coff + gn] = f2bf(v);
        }
    }
}

// ------------------------------ fc2 + log_softmax head (MFMA) ------------------------------

__global__ __launch_bounds__(256) void head_mfma_kernel(const u16* __restrict__ hid,
        const u16* __restrict__ w2t, const float* __restrict__ b2,
        float* __restrict__ out, int N) {
    int tile = blockIdx.x * 4 + (threadIdx.x >> 6);   // 16 nodes per tile
    int lane = threadIdx.x & 63;
    int l15 = lane & 15, lg = lane >> 4;
    int ntiles = (N + 15) / 16;
    if (tile >= ntiles) return;

    int anode = tile * 16 + l15;
    if (anode >= N) anode = N - 1;                    // clamp (dup compute, guarded store)
    const u16* Arow = hid + (size_t)anode * 256;
    const u16* Brow = w2t + (size_t)l15 * 256;        // col = l15

    f32x4 acc = (f32x4){0.f, 0.f, 0.f, 0.f};
#pragma unroll
    for (int k0 = 0; k0 < 256; k0 += 32) {
        bf16x8 a = *reinterpret_cast<const bf16x8*>(Arow + k0 + lg * 8);
        bf16x8 b = *reinterpret_cast<const bf16x8*>(Brow + k0 + lg * 8);
        acc = __builtin_amdgcn_mfma_f32_16x16x32_bf16(a, b, acc, 0, 0, 0);
    }
    float bcol = b2[l15];
#pragma unroll
    for (int r = 0; r < 4; ++r) {
        float v = acc[r] + bcol;
        float mx = v;
        mx = fmaxf(mx, __shfl_xor(mx, 1));
        mx = fmaxf(mx, __shfl_xor(mx, 2));
        mx = fmaxf(mx, __shfl_xor(mx, 4));
        mx = fmaxf(mx, __shfl_xor(mx, 8));
        float e = expf(v - mx);
        float s = e;
        s += __shfl_xor(s, 1);
        s += __shfl_xor(s, 2);
        s += __shfl_xor(s, 4);
        s += __shfl_xor(s, 8);
        float lse = mx + logf(s);
        int row = tile * 16 + lg * 4 + r;
        if (row < N) out[(size_t)row * 16 + l15] = v - lse;
    }
}

// ------------------------------ launch ------------------------------

extern "C" void kernel_launch(void* const* d_in, const int* in_sizes, int n_in,
                              void* d_out, int out_size, void* d_ws, size_t ws_size,
                              hipStream_t stream) {
    const float* x      = (const float*)d_in[0];
    const int*   ei     = (const int*)d_in[1];
    const int*   et     = (const int*)d_in[2];
    const float* rel_W  = (const float*)d_in[3];
    const float* root_W = (const float*)d_in[4];
    const float* bias   = (const float*)d_in[5];
    const float* fc1_w  = (const float*)d_in[6];
    const float* fc1_b  = (const float*)d_in[7];
    const float* fc2_w  = (const float*)d_in[8];
    const float* fc2_b  = (const float*)d_in[9];
    float* out = (float*)d_out;

    const int N = in_sizes[0] / D;   // 20000
    const int E = in_sizes[2];       // 500000
    const int* src = ei;
    const int* dst = ei + E;

    char* w = (char*)d_ws;
    u16* xb    = (u16*)w;  w += (size_t)N * 256 * 2;
    u16* h1b   = (u16*)w;  w += (size_t)N * 256 * 2;
    u16* h1c   = (u16*)w;  w += (size_t)N * 256 * 2;
    u16* hcatb = (u16*)w;  w += (size_t)N * 512 * 2;
    u16* aggA  = (u16*)w;  w += (size_t)N * 256 * 2;
    u16* aggB  = (u16*)w;  w += (size_t)N * 256 * 2;
    u16* Bcat  = (u16*)w;  w += (size_t)5 * 256 * 512 * 2;
    u16* fc2t  = (u16*)w;  w += (size_t)16 * 256 * 2;
    int* cnt     = (int*)w;  w += (size_t)4 * N * 4;
    int* row_ptr = (int*)w;  w += ((size_t)4 * N + 1) * 4;
    int* row_cur = (int*)w;  w += (size_t)4 * N * 4;
    int* eperm   = (int*)w;  w += (size_t)E * 4;
    int* bsum    = (int*)w;  w += 256 * 4;
    int* boff    = (int*)w;  w += 256 * 4;
    u16* hid = h1b;   // reuse after convs

    const int n_keys = 4 * N;
    const int nb = (n_keys + SCAN_BLK - 1) / SCAN_BLK;   // 20 for N=20000

    // per-relation CSR
    hipMemsetAsync(cnt, 0, (size_t)n_keys * 4, stream);
    hist_kernel<<<dim3((E + 255) / 256), dim3(256), 0, stream>>>(src, et, cnt, E, N);
    scan_reduce_kernel<<<dim3(nb), dim3(256), 0, stream>>>(cnt, bsum, n_keys);
    scan_sums_kernel<<<dim3(1), dim3(256), 0, stream>>>(bsum, boff, nb, row_ptr, n_keys);
    scan_out_kernel<<<dim3(nb), dim3(256), 0, stream>>>(cnt, boff, row_ptr, row_cur, n_keys);
    scatter_kernel<<<dim3((E + 255) / 256), dim3(256), 0, stream>>>(src, dst, et, row_cur, eperm, E, N);

    // fused prep
    {
        int total = N * 64 + 5 * 131072 + 4096;
        prep_kernel<<<dim3((total + 255) / 256), dim3(256), 0, stream>>>(
                x, rel_W, root_W, fc1_w, fc2_w, xb, Bcat, fc2t, N);
    }

    dim3 gblock(256);
    dim3 ngrid2((N + 3) / 4, 2);
    dim3 ggrid2((N + 63) / 64, 2, 2);   // BM=64, BN=128, z-batched pair
    dim3 ggrid1((N + 63) / 64, 2, 1);   // single GEMM

    // hop-0 aggregations (both read x)
    agg_kernel<<<ngrid2, gblock, 0, stream>>>(xb, xb, row_ptr, row_ptr + 2 * N, eperm,
                                              aggA, aggB, N);
    // hop-0 GEMMs for both metapaths in one launch:
    //   z=0: h1  = relu([aggA|x] @ B0 + b0)    z=1: h1c = relu([aggB|x] @ B2 + b2)
    gemm512b<<<ggrid2, gblock, 0, stream>>>(aggA, aggB, 256, xb, xb, 256,
                                            Bcat + 0 * 131072, Bcat + 2 * 131072, N,
                                            h1b, h1c, 256, 0,
                                            bias + 0 * 256, bias + 2 * 256);
    // hop-1 aggregations (mp0 from h1, mp1 from h1c)
    agg_kernel<<<ngrid2, gblock, 0, stream>>>(h1b, h1c, row_ptr + 1 * N, row_ptr + 3 * N,
                                              eperm, aggA, aggB, N);
    // hop-1 GEMMs, writing the two hcat halves:
    //   z=0: hcat[:,0:256]   z=1: hcat[:,256:512]
    gemm512b<<<ggrid2, gblock, 0, stream>>>(aggA, aggB, 256, h1b, h1c, 256,
                                            Bcat + 1 * 131072, Bcat + 3 * 131072, N,
                                            hcatb, hcatb, 512, 256,
                                            bias + 1 * 256, bias + 3 * 256);
    // fc1: hid = relu(hcat @ fc1 + b)
    gemm512b<<<ggrid1, gblock, 0, stream>>>(hcatb, hcatb, 512, hcatb + 256, hcatb + 256, 512,
                                            Bcat + 4 * 131072, Bcat + 4 * 131072, N,
                                            hid, hid, 256, 0, fc1_b, fc1_b);
    // head
    int ntiles = (N + 15) / 16;
    head_mfma_kernel<<<dim3((ntiles + 3) / 4), gblock, 0, stream>>>(hid, fc2t, fc2_b, out, N);
}

// Round 12
// 270.203 us; speedup vs baseline: 1.1768x; 1.0681x over previous
//
#include <hip/hip_runtime.h>
#include <hip/hip_bf16.h>

#define D 256
typedef unsigned short u16;
typedef __attribute__((ext_vector_type(8))) short bf16x8;
typedef __attribute__((ext_vector_type(4))) float f32x4;

__device__ inline u16 f2bf(float f) {
    unsigned u = __builtin_bit_cast(unsigned, f);
    unsigned r = (u + 0x7fff + ((u >> 16) & 1)) >> 16;   // RNE
    return (u16)r;
}
__device__ inline float bf2f(u16 u) {
    return __builtin_bit_cast(float, (unsigned)u << 16);
}

// ------------------------------ per-relation CSR build ------------------------------

__global__ void hist_kernel(const int* __restrict__ src, const int* __restrict__ et,
                            int* __restrict__ cnt, int E, int N) {
    int e = blockIdx.x * blockDim.x + threadIdx.x;
    if (e < E) {
        int r = et[e];
        if (r < 4) atomicAdd(&cnt[r * N + src[e]], 1);
    }
}

#define SCAN_BLK 4096

__global__ __launch_bounds__(256) void scan_reduce_kernel(const int* __restrict__ cnt,
        int* __restrict__ bsum, int n) {
    __shared__ int s[256];
    int base = blockIdx.x * SCAN_BLK;
    int t = threadIdx.x;
    int sum = 0;
    for (int i = t; i < SCAN_BLK; i += 256) {
        int idx = base + i;
        if (idx < n) sum += cnt[idx];
    }
    s[t] = sum;
    __syncthreads();
    for (int off = 128; off > 0; off >>= 1) {
        if (t < off) s[t] += s[t + off];
        __syncthreads();
    }
    if (t == 0) bsum[blockIdx.x] = s[0];
}

__global__ __launch_bounds__(256) void scan_sums_kernel(const int* __restrict__ bsum,
        int* __restrict__ boff, int nb, int* __restrict__ row_ptr, int n) {
    __shared__ int s[256];
    int t = threadIdx.x;
    s[t] = (t < nb) ? bsum[t] : 0;
    __syncthreads();
    for (int off = 1; off < 256; off <<= 1) {
        int v = (t >= off) ? s[t - off] : 0;
        __syncthreads();
        s[t] += v;
        __syncthreads();
    }
    if (t < nb) boff[t] = (t == 0) ? 0 : s[t - 1];
    if (t == 255) row_ptr[n] = s[255];
}

__global__ __launch_bounds__(256) void scan_out_kernel(const int* __restrict__ cnt,
        const int* __restrict__ boff, int* __restrict__ row_ptr,
        int* __restrict__ row_cur, int n) {
    __shared__ int stage[SCAN_BLK];
    __shared__ int part[256];
    int base = blockIdx.x * SCAN_BLK;
    int t = threadIdx.x;
    for (int i = t; i < SCAN_BLK; i += 256) {
        int idx = base + i;
        stage[i] = (idx < n) ? cnt[idx] : 0;
    }
    __syncthreads();
    int loc = 0;
#pragma unroll
    for (int j = 0; j < 16; ++j) loc += stage[t * 16 + j];
    part[t] = loc;
    __syncthreads();
    for (int off = 1; off < 256; off <<= 1) {
        int v = (t >= off) ? part[t - off] : 0;
        __syncthreads();
        part[t] += v;
        __syncthreads();
    }
    int run = boff[blockIdx.x] + ((t == 0) ? 0 : part[t - 1]);
#pragma unroll
    for (int j = 0; j < 16; ++j) {
        int idx = base + t * 16 + j;
        if (idx < n) {
            row_ptr[idx] = run;
            row_cur[idx] = run;
        }
        run += stage[t * 16 + j];
    }
}

__global__ void scatter_kernel(const int* __restrict__ src, const int* __restrict__ dst,
        const int* __restrict__ et, int* __restrict__ row_cur, int* __restrict__ eperm,
        int E, int N) {
    int e = blockIdx.x * blockDim.x + threadIdx.x;
    if (e < E) {
        int r = et[e];
        if (r < 4) {
            int pos = atomicAdd(&row_cur[r * N + src[e]], 1);
            eperm[pos] = dst[e];
        }
    }
}

// ------------------------------ fused prep (also zeroes cnt) ------------------------------

__global__ __launch_bounds__(256) void prep_kernel(const float* __restrict__ x,
        const float* __restrict__ rel_W, const float* __restrict__ root_W,
        const float* __restrict__ fc1_w, const float* __restrict__ fc2_w,
        u16* __restrict__ xb, u16* __restrict__ Bcat, u16* __restrict__ fc2t,
        int* __restrict__ cnt, int n_keys, int N) {
    int i = blockIdx.x * 256 + threadIdx.x;
    int nx = N * 64;                       // float4 count
    if (i < nx) {
        float4 v = reinterpret_cast<const float4*>(x)[i];
        ushort4 o;
        o.x = f2bf(v.x); o.y = f2bf(v.y); o.z = f2bf(v.z); o.w = f2bf(v.w);
        reinterpret_cast<ushort4*>(xb)[i] = o;
        return;
    }
    int j = i - nx;
    if (j < 5 * 131072) {
        int mi = j >> 17;                  // matrix 0..4
        int t = j & 131071;
        int k = t & 511;
        int n = t >> 9;                    // 0..255
        float v;
        if (mi < 4) {
            v = (k < 256) ? rel_W[(((size_t)mi * 5 + mi) * 256 + k) * 256 + n]
                          : root_W[((size_t)mi * 256 + (k - 256)) * 256 + n];
        } else {
            v = fc1_w[(size_t)k * 256 + n];
        }
        Bcat[(size_t)mi * 131072 + (size_t)n * 512 + k] = f2bf(v);
        return;
    }
    int h = j - 5 * 131072;
    if (h < 4096) {
        int k = h & 255;
        int col = h >> 8;
        fc2t[(size_t)col * 256 + k] = f2bf(fc2_w[(size_t)k * 16 + col]);
        return;
    }
    int c = h - 4096;
    if (c < n_keys) cnt[c] = 0;
}

// ------------------------------ mean aggregation (dual, 4-wide ILP) ------------------------------
// blockIdx.y selects (hA,rpA,outA) vs (hB,rpB,outB); fp32 accum, bf16 in/out.
// Edge loop unrolled 4x: 4 independent index loads then 4 independent row loads
// in flight, breaking the eperm->row dependent-latency chain.

__global__ __launch_bounds__(256) void agg_kernel(
        const u16* __restrict__ hA, const u16* __restrict__ hB,
        const int* __restrict__ rpA, const int* __restrict__ rpB,
        const int* __restrict__ eperm,
        u16* __restrict__ outA, u16* __restrict__ outB, int N) {
    int node = blockIdx.x * 4 + (threadIdx.x >> 6);
    int lane = threadIdx.x & 63;
    if (node >= N) return;
    const u16* h  = (blockIdx.y == 0) ? hA : hB;
    const int* rp = (blockIdx.y == 0) ? rpA : rpB;
    u16* outp     = (blockIdx.y == 0) ? outA : outB;

    int beg = rp[node];
    int end = rp[node + 1];
    const u16* hl = h + lane * 4;          // per-lane column base
    float a0 = 0.f, a1 = 0.f, a2 = 0.f, a3 = 0.f;
    int e = beg;
    for (; e + 4 <= end; e += 4) {
        int d0 = eperm[e + 0];
        int d1 = eperm[e + 1];
        int d2 = eperm[e + 2];
        int d3 = eperm[e + 3];
        ushort4 v0 = *reinterpret_cast<const ushort4*>(hl + (size_t)d0 * 256);
        ushort4 v1 = *reinterpret_cast<const ushort4*>(hl + (size_t)d1 * 256);
        ushort4 v2 = *reinterpret_cast<const ushort4*>(hl + (size_t)d2 * 256);
        ushort4 v3 = *reinterpret_cast<const ushort4*>(hl + (size_t)d3 * 256);
        a0 += bf2f(v0.x) + bf2f(v1.x) + bf2f(v2.x) + bf2f(v3.x);
        a1 += bf2f(v0.y) + bf2f(v1.y) + bf2f(v2.y) + bf2f(v3.y);
        a2 += bf2f(v0.z) + bf2f(v1.z) + bf2f(v2.z) + bf2f(v3.z);
        a3 += bf2f(v0.w) + bf2f(v1.w) + bf2f(v2.w) + bf2f(v3.w);
    }
    for (; e < end; ++e) {
        int d = eperm[e];
        ushort4 v = *reinterpret_cast<const ushort4*>(hl + (size_t)d * 256);
        a0 += bf2f(v.x); a1 += bf2f(v.y); a2 += bf2f(v.z); a3 += bf2f(v.w);
    }
    float inv = 1.0f / fmaxf((float)(end - beg), 1.0f);
    ushort4 o;
    o.x = f2bf(a0 * inv);
    o.y = f2bf(a1 * inv);
    o.z = f2bf(a2 * inv);
    o.w = f2bf(a3 * inv);
    *reinterpret_cast<ushort4*>(outp + (size_t)node * 256 + lane * 4) = o;
}

// ------------------------------ bf16 MFMA GEMM (K=512, NN=256, z-batched) ------------------------------
// out[m, coff+n] = relu( sum_k A[m,k]*Bt[n,k] + bias[n] ), A = [Alo | Ahi] split at k=256.
// BM=64 (4 waves x 16 rows), BN=128, BK=64 — proven config. blockIdx.z selects
// one of two independent GEMMs (wave-uniform selects); gridDim.z=1 for single.

__global__ __launch_bounds__(256) void gemm512b(
        const u16* __restrict__ Alo0, const u16* __restrict__ Alo1, int ldlo,
        const u16* __restrict__ Ahi0, const u16* __restrict__ Ahi1, int ldhi,
        const u16* __restrict__ Bt0, const u16* __restrict__ Bt1, int M,
        u16* __restrict__ out0, u16* __restrict__ out1, int ldo, int coff1,
        const float* __restrict__ bias0, const float* __restrict__ bias1) {
    __shared__ u16 Bs[128 * 64];   // 16 KB, physically swizzled

    const int z = blockIdx.z;
    const u16* Alo = z ? Alo1 : Alo0;
    const u16* Ahi = z ? Ahi1 : Ahi0;
    const u16* Bt  = z ? Bt1  : Bt0;
    u16* outp      = z ? out1 : out0;
    const float* bias = z ? bias1 : bias0;
    const int coff = z ? coff1 : 0;

    const int tid  = threadIdx.x;
    const int wave = tid >> 6, lane = tid & 63;
    const int l15 = lane & 15, lg = lane >> 4;
    const int m0 = blockIdx.x * 64 + wave * 16;
    const int n0 = blockIdx.y * 128;

    f32x4 acc[8];
#pragma unroll
    for (int j = 0; j < 8; ++j) acc[j] = (f32x4){0.f, 0.f, 0.f, 0.f};

    const int  arow = m0 + l15;
    const bool aval = arow < M;

#pragma unroll
    for (int k0 = 0; k0 < 512; k0 += 64) {
        __syncthreads();
#pragma unroll
        for (int i = 0; i < 4; ++i) {
            int phys = i * 4096 + tid * 16;
            int n    = phys >> 7;                       // B-row within tile (128 B rows)
            int cl   = (phys & 127) ^ ((n & 7) << 4);   // logical byte within row
            const u16* srcp = Bt + (size_t)(n0 + n) * 512 + k0 + (cl >> 1);
            __builtin_amdgcn_global_load_lds(
                (const __attribute__((address_space(1))) void*)srcp,
                (__attribute__((address_space(3))) void*)((char*)Bs + phys), 16, 0, 0);
        }
        const u16* Ab = (k0 < 256) ? (Alo + (size_t)arow * ldlo + k0)
                                   : (Ahi + (size_t)arow * ldhi + (k0 - 256));
        bf16x8 afr0, afr1;
        if (aval) {
            afr0 = *reinterpret_cast<const bf16x8*>(Ab + lg * 8);
            afr1 = *reinterpret_cast<const bf16x8*>(Ab + 32 + lg * 8);
        } else {
            afr0 = afr1 = (bf16x8){0, 0, 0, 0, 0, 0, 0, 0};
        }
        __syncthreads();   // drains vmcnt(0) -> staged tile ready
#pragma unroll
        for (int kk = 0; kk < 2; ++kk) {
#pragma unroll
            for (int j = 0; j < 8; ++j) {
                int n    = j * 16 + l15;
                int cl   = kk * 64 + lg * 16;
                int phys = n * 128 + (cl ^ ((n & 7) << 4));
                bf16x8 bfr = *reinterpret_cast<const bf16x8*>((const char*)Bs + phys);
                acc[j] = __builtin_amdgcn_mfma_f32_16x16x32_bf16(kk ? afr1 : afr0, bfr, acc[j], 0, 0, 0);
            }
        }
    }

    // epilogue: D col = lane&15, row = (lane>>4)*4 + reg  [m89/m91 verified]
    const int orow = m0 + lg * 4;
#pragma unroll
    for (int j = 0; j < 8; ++j) {
        int gn = n0 + j * 16 + l15;
        float b = bias[gn];
#pragma unroll
        for (int r = 0; r < 4; ++r) {
            int m = orow + r;
            if (m >= M) continue;
            float v = fmaxf(acc[j][r] + b, 0.0f);
            outp[(size_t)m * ldo + coff + gn] = f2bf(v);
        }
    }
}

// ------------------------------ fc2 + log_softmax head (MFMA) ------------------------------

__global__ __launch_bounds__(256) void head_mfma_kernel(const u16* __restrict__ hid,
        const u16* __restrict__ w2t, const float* __restrict__ b2,
        float* __restrict__ out, int N) {
    int tile = blockIdx.x * 4 + (threadIdx.x >> 6);   // 16 nodes per tile
    int lane = threadIdx.x & 63;
    int l15 = lane & 15, lg = lane >> 4;
    int ntiles = (N + 15) / 16;
    if (tile >= ntiles) return;

    int anode = tile * 16 + l15;
    if (anode >= N) anode = N - 1;                    // clamp (dup compute, guarded store)
    const u16* Arow = hid + (size_t)anode * 256;
    const u16* Brow = w2t + (size_t)l15 * 256;        // col = l15

    f32x4 acc = (f32x4){0.f, 0.f, 0.f, 0.f};
#pragma unroll
    for (int k0 = 0; k0 < 256; k0 += 32) {
        bf16x8 a = *reinterpret_cast<const bf16x8*>(Arow + k0 + lg * 8);
        bf16x8 b = *reinterpret_cast<const bf16x8*>(Brow + k0 + lg * 8);
        acc = __builtin_amdgcn_mfma_f32_16x16x32_bf16(a, b, acc, 0, 0, 0);
    }
    float bcol = b2[l15];
#pragma unroll
    for (int r = 0; r < 4; ++r) {
        float v = acc[r] + bcol;
        float mx = v;
        mx = fmaxf(mx, __shfl_xor(mx, 1));
        mx = fmaxf(mx, __shfl_xor(mx, 2));
        mx = fmaxf(mx, __shfl_xor(mx, 4));
        mx = fmaxf(mx, __shfl_xor(mx, 8));
        float e = expf(v - mx);
        float s = e;
        s += __shfl_xor(s, 1);
        s += __shfl_xor(s, 2);
        s += __shfl_xor(s, 4);
        s += __shfl_xor(s, 8);
        float lse = mx + logf(s);
        int row = tile * 16 + lg * 4 + r;
        if (row < N) out[(size_t)row * 16 + l15] = v - lse;
    }
}

// ------------------------------ launch ------------------------------

extern "C" void kernel_launch(void* const* d_in, const int* in_sizes, int n_in,
                              void* d_out, int out_size, void* d_ws, size_t ws_size,
                              hipStream_t stream) {
    const float* x      = (const float*)d_in[0];
    const int*   ei     = (const int*)d_in[1];
    const int*   et     = (const int*)d_in[2];
    const float* rel_W  = (const float*)d_in[3];
    const float* root_W = (const float*)d_in[4];
    const float* bias   = (const float*)d_in[5];
    const float* fc1_w  = (const float*)d_in[6];
    const float* fc1_b  = (const float*)d_in[7];
    const float* fc2_w  = (const float*)d_in[8];
    const float* fc2_b  = (const float*)d_in[9];
    float* out = (float*)d_out;

    const int N = in_sizes[0] / D;   // 20000
    const int E = in_sizes[2];       // 500000
    const int* src = ei;
    const int* dst = ei + E;

    char* w = (char*)d_ws;
    u16* xb    = (u16*)w;  w += (size_t)N * 256 * 2;
    u16* h1b   = (u16*)w;  w += (size_t)N * 256 * 2;
    u16* h1c   = (u16*)w;  w += (size_t)N * 256 * 2;
    u16* hcatb = (u16*)w;  w += (size_t)N * 512 * 2;
    u16* aggA  = (u16*)w;  w += (size_t)N * 256 * 2;
    u16* aggB  = (u16*)w;  w += (size_t)N * 256 * 2;
    u16* Bcat  = (u16*)w;  w += (size_t)5 * 256 * 512 * 2;
    u16* fc2t  = (u16*)w;  w += (size_t)16 * 256 * 2;
    int* cnt     = (int*)w;  w += (size_t)4 * N * 4;
    int* row_ptr = (int*)w;  w += ((size_t)4 * N + 1) * 4;
    int* row_cur = (int*)w;  w += (size_t)4 * N * 4;
    int* eperm   = (int*)w;  w += (size_t)E * 4;
    int* bsum    = (int*)w;  w += 256 * 4;
    int* boff    = (int*)w;  w += 256 * 4;
    u16* hid = h1b;   // reuse after convs

    const int n_keys = 4 * N;
    const int nb = (n_keys + SCAN_BLK - 1) / SCAN_BLK;   // 20 for N=20000

    // fused prep (also zeroes cnt) must precede hist
    {
        int total = N * 64 + 5 * 131072 + 4096 + n_keys;
        prep_kernel<<<dim3((total + 255) / 256), dim3(256), 0, stream>>>(
                x, rel_W, root_W, fc1_w, fc2_w, xb, Bcat, fc2t, cnt, n_keys, N);
    }

    // per-relation CSR
    hist_kernel<<<dim3((E + 255) / 256), dim3(256), 0, stream>>>(src, et, cnt, E, N);
    scan_reduce_kernel<<<dim3(nb), dim3(256), 0, stream>>>(cnt, bsum, n_keys);
    scan_sums_kernel<<<dim3(1), dim3(256), 0, stream>>>(bsum, boff, nb, row_ptr, n_keys);
    scan_out_kernel<<<dim3(nb), dim3(256), 0, stream>>>(cnt, boff, row_ptr, row_cur, n_keys);
    scatter_kernel<<<dim3((E + 255) / 256), dim3(256), 0, stream>>>(src, dst, et, row_cur, eperm, E, N);

    dim3 gblock(256);
    dim3 ngrid2((N + 3) / 4, 2);
    dim3 ggrid2((N + 63) / 64, 2, 2);   // BM=64, BN=128, z-batched pair
    dim3 ggrid1((N + 63) / 64, 2, 1);   // single GEMM

    // hop-0 aggregations (both read x)
    agg_kernel<<<ngrid2, gblock, 0, stream>>>(xb, xb, row_ptr, row_ptr + 2 * N, eperm,
                                              aggA, aggB, N);
    // hop-0 GEMMs for both metapaths in one launch:
    //   z=0: h1  = relu([aggA|x] @ B0 + b0)    z=1: h1c = relu([aggB|x] @ B2 + b2)
    gemm512b<<<ggrid2, gblock, 0, stream>>>(aggA, aggB, 256, xb, xb, 256,
                                            Bcat + 0 * 131072, Bcat + 2 * 131072, N,
                                            h1b, h1c, 256, 0,
                                            bias + 0 * 256, bias + 2 * 256);
    // hop-1 aggregations (mp0 from h1, mp1 from h1c)
    agg_kernel<<<ngrid2, gblock, 0, stream>>>(h1b, h1c, row_ptr + 1 * N, row_ptr + 3 * N,
                                              eperm, aggA, aggB, N);
    // hop-1 GEMMs, writing the two hcat halves:
    //   z=0: hcat[:,0:256]   z=1: hcat[:,256:512]
    gemm512b<<<ggrid2, gblock, 0, stream>>>(aggA, aggB, 256, h1b, h1c, 256,
                                            Bcat + 1 * 131072, Bcat + 3 * 131072, N,
                                            hcatb, hcatb, 512, 256,
                                            bias + 1 * 256, bias + 3 * 256);
    // fc1: hid = relu(hcat @ fc1 + b)
    gemm512b<<<ggrid1, gblock, 0, stream>>>(hcatb, hcatb, 512, hcatb + 256, hcatb + 256, 512,
                                            Bcat + 4 * 131072, Bcat + 4 * 131072, N,
                                            hid, hid, 256, 0, fc1_b, fc1_b);
    // head
    int ntiles = (N + 15) / 16;
    head_mfma_kernel<<<dim3((ntiles + 3) / 4), gblock, 0, stream>>>(hid, fc2t, fc2_b, out, N);
}